// Round 4
// baseline (284.998 us; speedup 1.0000x reference)
//
#include <hip/hip_runtime.h>

// MultiHeadAttention: B=4 T=2048 C=1024 H=16 D=64, fp32 in/out, bf16 MFMA internally.
//
// Pipeline (all on `stream`):
//   1. cast_f32_bf16:    x (fp32 [8192,1024]) -> xb bf16
//   2. transpose_cast_w: Wq,Wk,Wv,Wp (fp32 [K,N]) -> WT bf16 [N,K] (B^T form)
//   3. gemm_qkv (R8):    256x256-tile 8-phase GEMM; Q pre-scaled by
//                        0.125*log2(e) (R7); V written TRANSPOSED as Vt
//                        [b,h,d,t] (kt-permuted, R6)
//   4. attn_kernel:      flash attention, operand-swapped, 64 q/wave (R7)
//   5. gemm_proj (R8):   out = attn @ Wp^T + bp, fp32 -> d_out
//
// R6: P LDS round-trip eliminated via bf16x2 pack + v_permlane16_swap_b32;
//     V^T stored kt-permuted: pos = (quad&1)<<5 | (((quad>>1)<<1|(mt&1))<<3)
//     | ((mt>>1)<<2) (+r) within each 64-aligned t-block.
// R7: 64 q/wave attn (4 q-sets share K/V frags); logit scale folded into Q.
// R8: GEMMs ported from the m97 128^2 2-barrier structure (~400 TF at this
//     shape; vmcnt(0) drain per K-step) to the 256^2 8-phase schedule:
//     BM=BN=256 BK=64, 8 waves (2Mx4N), 128 KiB LDS double-buffer staged by
//     global_load_lds, st_16x32 XOR swizzle (write side: source-unit permute
//     s^=((s>>5)&1)<<1 since gload_lds writes linearly; read side:
//     elem ^= ((lr>>2)&1)<<4, lane-constant), counted vmcnt(6) once per
//     K-tile (vmcnt(0) only at the last boundary), raw s_barrier +
//     sched_barrier(0) phase fences, s_setprio(1) around each 16-MFMA
//     cluster. Issue schedule (verified): per tile t phases issue
//     {B-H1(t+1), A-lo(t+2), A-hi(t+2), B-H0(t+2)}, each after the target
//     LDS region's last reader phase; prologue = 14 loads + vmcnt(6).

#define B_ 4
#define T_ 2048
#define C_ 1024
#define H_ 16
#define D_ 64

// 0.125 * log2(e): attention scale folded into Q at projection time (R7b).
#define QSCALE 0.18033688011112042f

typedef float  f32x4  __attribute__((ext_vector_type(4)));
typedef __bf16 bf16x8 __attribute__((ext_vector_type(8)));
typedef __bf16 bf16x4 __attribute__((ext_vector_type(4)));
typedef __bf16 bf16x2 __attribute__((ext_vector_type(2)));
typedef unsigned uint2v __attribute__((ext_vector_type(2)));

typedef const __attribute__((address_space(1))) void gv_t;
typedef __attribute__((address_space(3))) void lds_t;

__device__ __forceinline__ void async_load16(const void* g, void* l) {
  __builtin_amdgcn_global_load_lds((gv_t*)g, (lds_t*)l, 16, 0, 0);
}

__device__ __forceinline__ float fast_exp2(float x) {
#if __has_builtin(__builtin_amdgcn_exp2f)
  return __builtin_amdgcn_exp2f(x);
#else
  return exp2f(x);
#endif
}

// v_permlane16_swap_b32: newA rows = [A0,B0,A2,B2], newB rows = [A1,B1,A3,B3]
__device__ __forceinline__ void pl16_swap(unsigned& a, unsigned& b) {
#if __has_builtin(__builtin_amdgcn_permlane16_swap)
  uint2v r = __builtin_amdgcn_permlane16_swap(a, b, false, false);
  a = r[0];
  b = r[1];
#else
  asm("v_permlane16_swap_b32 %0, %1" : "+v"(a), "+v"(b));
#endif
}

// ---------------------------------------------------------------- cast x
__global__ __launch_bounds__(256) void cast_f32_bf16(
    const float* __restrict__ in, __bf16* __restrict__ out, int n) {
  int i = (blockIdx.x * 256 + threadIdx.x) * 8;
  if (i >= n) return;
  float4 a = *(const float4*)(in + i);
  float4 b = *(const float4*)(in + i + 4);
  bf16x8 o;
  o[0] = (__bf16)a.x; o[1] = (__bf16)a.y; o[2] = (__bf16)a.z; o[3] = (__bf16)a.w;
  o[4] = (__bf16)b.x; o[5] = (__bf16)b.y; o[6] = (__bf16)b.z; o[7] = (__bf16)b.w;
  *(bf16x8*)(out + i) = o;
}

// ------------------------------------------- W [K,N] fp32 -> W^T [N,K] bf16
__global__ __launch_bounds__(256) void transpose_cast_w(
    const float* __restrict__ W0, const float* __restrict__ W1,
    const float* __restrict__ W2, const float* __restrict__ W3,
    __bf16* __restrict__ out) {
  int z = blockIdx.z;
  const float* W = (z == 0) ? W0 : (z == 1) ? W1 : (z == 2) ? W2 : W3;
  __bf16* o = out + (size_t)z * (C_ * C_);
  __shared__ __align__(16) __bf16 sT[64][72];
  int tid = threadIdx.x;
  int n0 = blockIdx.x * 64, k0 = blockIdx.y * 64;
#pragma unroll
  for (int i = 0; i < 4; i++) {
    int s = tid + i * 256;
    int kr = s >> 4, nc = (s & 15) * 4;
    float4 v = *(const float4*)&W[(size_t)(k0 + kr) * C_ + n0 + nc];
    bf16x4 t;
    t[0] = (__bf16)v.x; t[1] = (__bf16)v.y; t[2] = (__bf16)v.z; t[3] = (__bf16)v.w;
    *(bf16x4*)&sT[kr][nc] = t;
  }
  __syncthreads();
#pragma unroll
  for (int i = 0; i < 2; i++) {
    int s = tid + i * 256;
    int nr = s >> 3, kc = (s & 7) * 8;
    bf16x8 ov;
#pragma unroll
    for (int j = 0; j < 8; j++) ov[j] = sT[kc + j][nr];
    *(bf16x8*)&o[(size_t)(n0 + nr) * C_ + k0 + kc] = ov;
  }
}

// =================== R8: 256x256 8-phase GEMM (K = 1024, N = 1024 per z) ===
// C[M,N] = (A[M,1024] @ Bt[N,1024]^T + bias) * scale
// 512 threads = 8 waves (wr = wave>>2 in {0,1}, wc = wave&3 in {0..3}).
// Per-wave output 128x64: acc[mt(8)][nt(4)] f32x4.
// LDS: sA[2][256][64] + sB[2][256][64] bf16 = 128 KiB (dynamic).
// st_16x32 swizzle: LDS elem ^= ((row>>2)&1)<<4; staged via source-unit
// permute s' = s ^ (((s>>5)&1)<<1) (involution verified).
#define PHASE_FENCE() do { __builtin_amdgcn_sched_barrier(0); \
                           __builtin_amdgcn_s_barrier(); } while (0)

template <typename OutT, int EPI>
__device__ __forceinline__ void gemm256_body(
    const __bf16* __restrict__ A, const __bf16* __restrict__ Bt,
    const float* __restrict__ bias, OutT* __restrict__ C, int N, float scale) {
  extern __shared__ __align__(16) char smem[];
  __bf16* sAe = (__bf16*)smem;              // [2][256][64]
  __bf16* sBe = (__bf16*)(smem + 65536);    // [2][256][64]
  const int NT = 16;                        // K/64
  int tid = threadIdx.x, lane = tid & 63, wave = tid >> 6;
  int lr = lane & 15, quad = lane >> 4;
  int wr = wave >> 2, wc = wave & 3;
  int m0 = blockIdx.y * 256, n0 = blockIdx.x * 256;
  int lswz = ((lr >> 2) & 1) << 4;          // read-side swizzle (elems)

  // staging maps: load l covers units s = tid + l*512; source permuted.
  int srcRow[2], srcCol[2], ldsS[2];
#pragma unroll
  for (int l = 0; l < 2; l++) {
    int s = tid + l * 512;
    int s2 = s ^ (((s >> 5) & 1) << 1);
    srcRow[l] = s2 >> 3;
    srcCol[l] = (s2 & 7) * 8;
    ldsS[l] = s * 8;
  }
  const __bf16* Ag = A + (size_t)m0 * 1024;
  const __bf16* Bg = Bt + (size_t)n0 * 1024;

  auto issueA = [&](int tt, int l) {  // one A quarter-load in each half
    int slot = tt & 1;
    const __bf16* g = Ag + (size_t)srcRow[l] * 1024 + tt * 64 + srcCol[l];
    async_load16(g, sAe + slot * 16384 + ldsS[l]);
    async_load16(g + (size_t)128 * 1024, sAe + slot * 16384 + 8192 + ldsS[l]);
  };
  auto issueB = [&](int tt, int Hh) {  // one B half (both loads)
    int slot = tt & 1;
#pragma unroll
    for (int l = 0; l < 2; l++) {
      const __bf16* g =
          Bg + (size_t)(Hh * 128 + srcRow[l]) * 1024 + tt * 64 + srcCol[l];
      async_load16(g, sBe + slot * 16384 + Hh * 8192 + ldsS[l]);
    }
  };

  const f32x4 zero = {0.f, 0.f, 0.f, 0.f};
  f32x4 acc[8][4];
#pragma unroll
  for (int i = 0; i < 8; i++)
#pragma unroll
    for (int j = 0; j < 4; j++) acc[i][j] = zero;

  bf16x8 af0[4][2], af1[4][2], bf01[2][2], bf23[2][2];

  auto rdA = [&](int slot, int msub, bf16x8(&af)[4][2]) {
    int rbase = wr * 128 + msub * 64;
#pragma unroll
    for (int mt = 0; mt < 4; mt++)
#pragma unroll
      for (int j = 0; j < 2; j++) {
        int row = rbase + mt * 16 + lr;
        int e = (row * 64 + j * 32 + quad * 8) ^ lswz;
        af[mt][j] = *(const bf16x8*)&sAe[slot * 16384 + e];
      }
  };
  auto rdB = [&](int slot, int nsub, bf16x8(&bf)[2][2]) {
    int rbase = wc * 64 + nsub * 32;
#pragma unroll
    for (int ntl = 0; ntl < 2; ntl++)
#pragma unroll
      for (int j = 0; j < 2; j++) {
        int row = rbase + ntl * 16 + lr;
        int e = (row * 64 + j * 32 + quad * 8) ^ lswz;
        bf[ntl][j] = *(const bf16x8*)&sBe[slot * 16384 + e];
      }
  };

#define MF16(AF, BF, MB, NB)                                              \
  do {                                                                    \
    __builtin_amdgcn_s_setprio(1);                                        \
    _Pragma("unroll") for (int mt = 0; mt < 4; mt++)                      \
        _Pragma("unroll") for (int ntl = 0; ntl < 2; ntl++)               \
            _Pragma("unroll") for (int j = 0; j < 2; j++)                 \
                acc[(MB) + mt][(NB) + ntl] =                              \
                    __builtin_amdgcn_mfma_f32_16x16x32_bf16(              \
                        AF[mt][j], BF[ntl][j], acc[(MB) + mt][(NB) + ntl],\
                        0, 0, 0);                                         \
    __builtin_amdgcn_s_setprio(0);                                        \
  } while (0)

  // prologue: tile0 fully + tile1's {A-lo, A-hi, B-H0} = 14 loads.
  issueA(0, 0); issueA(0, 1); issueB(0, 0); issueB(0, 1);
  issueA(1, 0); issueA(1, 1); issueB(1, 0);
  asm volatile("s_waitcnt vmcnt(6)" ::: "memory");  // tile0's 8 loads done
  PHASE_FENCE();

  for (int t = 0; t < NT; t++) {
    int slot = t & 1;
    // phase 0: quadrant (ms0, ns0)
    rdA(slot, 0, af0);
    rdB(slot, 0, bf01);
    if (t + 1 < NT) issueB(t + 1, 1);
    PHASE_FENCE();
    MF16(af0, bf01, 0, 0);
    PHASE_FENCE();
    // phase 1: (ms1, ns0)
    rdA(slot, 1, af1);
    if (t + 2 < NT) issueA(t + 2, 0);
    PHASE_FENCE();
    MF16(af1, bf01, 4, 0);
    PHASE_FENCE();
    // phase 2: (ms1, ns1)
    rdB(slot, 1, bf23);
    if (t + 2 < NT) issueA(t + 2, 1);
    PHASE_FENCE();
    MF16(af1, bf23, 4, 2);
    PHASE_FENCE();
    // phase 3: (ms0, ns1); counted vmcnt guarantees tile t+1 resident
    if (t + 2 < NT) issueB(t + 2, 0);
    if (t < NT - 2) {
      asm volatile("s_waitcnt vmcnt(6)" ::: "memory");
    } else {
      asm volatile("s_waitcnt vmcnt(0)" ::: "memory");
    }
    PHASE_FENCE();
    MF16(af0, bf23, 0, 2);
    PHASE_FENCE();
  }

  // epilogue. C/D layout: col = lane&15 (n), row = quad*4+reg (m) [m89/m91]
  if (EPI == 0) {
#pragma unroll
    for (int mt = 0; mt < 8; mt++) {
#pragma unroll
      for (int nt = 0; nt < 4; nt++) {
        int n = n0 + wc * 64 + nt * 16 + lr;
        float bv = bias[n];
#pragma unroll
        for (int r = 0; r < 4; r++) {
          int m = m0 + wr * 128 + mt * 16 + quad * 4 + r;
          C[(size_t)m * N + n] = (OutT)((acc[mt][nt][r] + bv) * scale);
        }
      }
    }
  } else {
    // V^T: Vt[(b*16+h)*64+d][t_perm]; R6 permutation per 64-aligned t-block.
    int bb = m0 >> 11;
    int base = (m0 & (T_ - 1)) + wr * 128;
    __bf16* Ct = (__bf16*)C;
#pragma unroll
    for (int mt = 0; mt < 8; mt++) {
      int mtl = mt & 3;
      int pos = ((quad & 1) << 5) | ((((quad >> 1) << 1) | (mtl & 1)) << 3) |
                ((mtl >> 1) << 2);
      int tcol = base + (mt >> 2) * 64 + pos;
#pragma unroll
      for (int nt = 0; nt < 4; nt++) {
        int n = n0 + wc * 64 + nt * 16 + lr;
        float bv = bias[n];
        bf16x4 ov;
#pragma unroll
        for (int r = 0; r < 4; r++) ov[r] = (__bf16)(acc[mt][nt][r] + bv);
        *(bf16x4*)&Ct[((size_t)bb * C_ + n) * T_ + tcol] = ov;
      }
    }
  }
}

__global__ __launch_bounds__(512, 2) void gemm256_qkv_kernel(
    const __bf16* __restrict__ A, const __bf16* __restrict__ WT,
    const float* __restrict__ b0, const float* __restrict__ b1,
    const float* __restrict__ b2, __bf16* __restrict__ qkbase,
    __bf16* __restrict__ Vt) {
  int z = blockIdx.z;
  if (z == 2) {
    gemm256_body<__bf16, 1>(A, WT + (size_t)2 * C_ * C_, b2, Vt, C_, 1.0f);
  } else {
    const float* bias = (z == 0) ? b0 : b1;
    float scale = (z == 0) ? QSCALE : 1.0f;
    gemm256_body<__bf16, 0>(A, WT + (size_t)z * C_ * C_, bias,
                            qkbase + (size_t)z * (B_ * T_) * C_, C_, scale);
  }
}

__global__ __launch_bounds__(512, 2) void gemm256_proj_kernel(
    const __bf16* __restrict__ A, const __bf16* __restrict__ Bt,
    const float* __restrict__ bias, float* __restrict__ C) {
  gemm256_body<float, 0>(A, Bt, bias, C, C_, 1.0f);
}

// ----------------- attention, operand-swapped, no-max softmax, 64 q / wave
__global__ __launch_bounds__(256) void attn_kernel(
    const __bf16* __restrict__ Q, const __bf16* __restrict__ K,
    const __bf16* __restrict__ Vt, __bf16* __restrict__ O) {
  __shared__ __align__(16) __bf16 sK[64 * 72];      // [kt][d]
  __shared__ __align__(16) __bf16 sV[64 * 72];      // [d][kt_permuted]
  int tid = threadIdx.x, wave = tid >> 6, lane = tid & 63;
  int lr = lane & 15, quad = lane >> 4;
  int bh = blockIdx.y;
  int b = bh >> 4, h = bh & 15;
  int qw = blockIdx.x * 256 + wave * 64;

  bf16x8 aq[4][2];
#pragma unroll
  for (int s = 0; s < 4; s++) {
    const __bf16* qp =
        Q + ((size_t)(b * T_ + qw + s * 16 + lr)) * C_ + h * D_ + quad * 8;
    aq[s][0] = *(const bf16x8*)qp;
    aq[s][1] = *(const bf16x8*)(qp + 32);
  }

  bf16x8 onesf;
#pragma unroll
  for (int j = 0; j < 8; j++) onesf[j] = (__bf16)1.0f;

  const f32x4 zero = {0.f, 0.f, 0.f, 0.f};
  f32x4 accO[4][4];
  f32x4 accL[4] = {zero, zero, zero, zero};
#pragma unroll
  for (int s = 0; s < 4; s++)
#pragma unroll
    for (int d = 0; d < 4; d++) accO[s][d] = zero;

  int srow[2], sc8[2];
#pragma unroll
  for (int i = 0; i < 2; i++) {
    int s = tid + i * 256;
    srow[i] = s >> 3;
    sc8[i] = (s & 7) * 8;
  }

  bf16x8 kreg[2], vreg[2];
#pragma unroll
  for (int i = 0; i < 2; i++) {
    kreg[i] = *(const bf16x8*)(K + ((size_t)(b * T_ + srow[i])) * C_ + h * D_ + sc8[i]);
    vreg[i] = *(const bf16x8*)(Vt + ((size_t)(bh * D_ + srow[i])) * T_ + sc8[i]);
  }

  for (int k0 = 0; k0 < T_; k0 += 64) {
    __syncthreads();
#pragma unroll
    for (int i = 0; i < 2; i++) {
      *(bf16x8*)&sK[srow[i] * 72 + sc8[i]] = kreg[i];
      *(bf16x8*)&sV[srow[i] * 72 + sc8[i]] = vreg[i];
    }
    __syncthreads();

    if (k0 + 64 < T_) {
      int kn = k0 + 64;
#pragma unroll
      for (int i = 0; i < 2; i++) {
        kreg[i] = *(const bf16x8*)(K + ((size_t)(b * T_ + kn + srow[i])) * C_ + h * D_ + sc8[i]);
        vreg[i] = *(const bf16x8*)(Vt + ((size_t)(bh * D_ + srow[i])) * T_ + kn + sc8[i]);
      }
    }

    bf16x8 bkf[4][2];
#pragma unroll
    for (int nt = 0; nt < 4; nt++) {
      bkf[nt][0] = *(const bf16x8*)&sK[(nt * 16 + lr) * 72 + quad * 8];
      bkf[nt][1] = *(const bf16x8*)&sK[(nt * 16 + lr) * 72 + 32 + quad * 8];
    }

    bf16x8 bpA[4], bpB[4];
#pragma unroll
    for (int s = 0; s < 4; s++) {
      unsigned pw[4][2];
#pragma unroll
      for (int nt = 0; nt < 4; nt++) {
        f32x4 z = zero;
        z = __builtin_amdgcn_mfma_f32_16x16x32_bf16(bkf[nt][0], aq[s][0], z, 0, 0, 0);
        z = __builtin_amdgcn_mfma_f32_16x16x32_bf16(bkf[nt][1], aq[s][1], z, 0, 0, 0);
        union { bf16x2 h; unsigned u; } t0, t1;
        t0.h[0] = (__bf16)fast_exp2(z[0]);
        t0.h[1] = (__bf16)fast_exp2(z[1]);
        t1.h[0] = (__bf16)fast_exp2(z[2]);
        t1.h[1] = (__bf16)fast_exp2(z[3]);
        pw[nt][0] = t0.u;
        pw[nt][1] = t1.u;
      }
      unsigned a0 = pw[0][0], b0 = pw[1][0]; pl16_swap(a0, b0);
      unsigned a1 = pw[0][1], b1 = pw[1][1]; pl16_swap(a1, b1);
      unsigned a2 = pw[2][0], b2 = pw[3][0]; pl16_swap(a2, b2);
      unsigned a3 = pw[2][1], b3 = pw[3][1]; pl16_swap(a3, b3);
      union { unsigned u[4]; bf16x8 v; } pA, pB;
      pA.u[0] = a0; pA.u[1] = a1; pA.u[2] = a2; pA.u[3] = a3;
      pB.u[0] = b0; pB.u[1] = b1; pB.u[2] = b2; pB.u[3] = b3;
      bpA[s] = pA.v;
      bpB[s] = pB.v;
      accL[s] = __builtin_amdgcn_mfma_f32_16x16x32_bf16(onesf, bpA[s], accL[s], 0, 0, 0);
      accL[s] = __builtin_amdgcn_mfma_f32_16x16x32_bf16(onesf, bpB[s], accL[s], 0, 0, 0);
    }
#pragma unroll
    for (int dt = 0; dt < 4; dt++) {
      bf16x8 av0 = *(const bf16x8*)&sV[(dt * 16 + lr) * 72 + quad * 8];
      bf16x8 av1 = *(const bf16x8*)&sV[(dt * 16 + lr) * 72 + 32 + quad * 8];
#pragma unroll
      for (int s = 0; s < 4; s++) {
        accO[s][dt] = __builtin_amdgcn_mfma_f32_16x16x32_bf16(av0, bpA[s], accO[s][dt], 0, 0, 0);
        accO[s][dt] = __builtin_amdgcn_mfma_f32_16x16x32_bf16(av1, bpB[s], accO[s][dt], 0, 0, 0);
      }
    }
  }

#pragma unroll
  for (int s = 0; s < 4; s++) {
    float inv = 1.0f / accL[s][0];
    __bf16* op =
        O + ((size_t)(b * T_ + qw + s * 16 + lr)) * C_ + h * D_ + quad * 4;
#pragma unroll
    for (int dt = 0; dt < 4; dt++) {
      bf16x4 ov;
#pragma unroll
      for (int r = 0; r < 4; r++) ov[r] = (__bf16)(accO[s][dt][r] * inv);
      *(bf16x4*)&op[dt * 16] = ov;
    }
  }
}

// ------------------------------------------------------------------ launch
extern "C" void kernel_launch(void* const* d_in, const int* in_sizes, int n_in,
                              void* d_out, int out_size, void* d_ws, size_t ws_size,
                              hipStream_t stream) {
  const float* x  = (const float*)d_in[0];
  const float* Wq = (const float*)d_in[1];
  const float* bq = (const float*)d_in[2];
  const float* Wk = (const float*)d_in[3];
  const float* bk = (const float*)d_in[4];
  const float* Wv = (const float*)d_in[5];
  const float* bv = (const float*)d_in[6];
  const float* Wp = (const float*)d_in[7];
  const float* bp = (const float*)d_in[8];
  float* out = (float*)d_out;

  static bool attr_done = false;
  if (!attr_done) {
    (void)hipFuncSetAttribute((const void*)gemm256_qkv_kernel,
                              hipFuncAttributeMaxDynamicSharedMemorySize,
                              131072);
    (void)hipFuncSetAttribute((const void*)gemm256_proj_kernel,
                              hipFuncAttributeMaxDynamicSharedMemorySize,
                              131072);
    attr_done = true;
  }

  char* ws = (char*)d_ws;
  const size_t MB = 1024 * 1024;
  __bf16* xb    = (__bf16*)(ws + 0 * MB);   // 16 MB
  __bf16* WT    = (__bf16*)(ws + 16 * MB);  // 8 MB
  __bf16* Qb    = (__bf16*)(ws + 24 * MB);  // Q 16 MB (pre-scaled by QSCALE)
  __bf16* Kb    = Qb + (size_t)(B_ * T_) * C_;   // K 16 MB
  __bf16* Vt    = Kb + (size_t)(B_ * T_) * C_;   // V^T 16 MB (R6-permuted)
  __bf16* attnb = (__bf16*)(ws + 72 * MB);  // 16 MB; total 88 MB
  __bf16* WpT   = WT + (size_t)3 * C_ * C_;

  cast_f32_bf16<<<dim3(4096), dim3(256), 0, stream>>>(x, xb, B_ * T_ * C_);
  transpose_cast_w<<<dim3(16, 16, 4), dim3(256), 0, stream>>>(Wq, Wk, Wv, Wp, WT);
  gemm256_qkv_kernel<<<dim3(4, 32, 3), dim3(512), 131072, stream>>>(
      xb, WT, bq, bk, bv, Qb, Vt);
  attn_kernel<<<dim3(8, 64), dim3(256), 0, stream>>>(Qb, Kb, Vt, attnb);
  gemm256_proj_kernel<<<dim3(4, 32), dim3(512), 131072, stream>>>(
      attnb, WpT, bp, out);
}

// Round 5
// 270.572 us; speedup vs baseline: 1.0533x; 1.0533x over previous
//
#include <hip/hip_runtime.h>

// MultiHeadAttention: B=4 T=2048 C=1024 H=16 D=64, fp32 in/out, bf16 MFMA internally.
//
// Pipeline (all on `stream`):
//   1. cast_f32_bf16:    x (fp32 [8192,1024]) -> xb bf16
//   2. transpose_cast_w: Wq,Wk,Wv,Wp (fp32 [K,N]) -> WT bf16 [N,K] (B^T form)
//   3. gemm_qkv:         Q/K = xb @ W^T + b (bf16 [b,t,h,d]); Q pre-scaled by
//                        0.125*log2(e) (R7); V written TRANSPOSED as Vt
//                        [b,h,d,t] (kt-permuted, R6)
//   4. attn_kernel:      flash attention, operand-swapped, 64 q/wave (R7),
//                        XCD-clustered grid + raw barriers (R9)
//   5. gemm_proj:        out = attn @ Wp^T + bp, fp32 -> d_out
//
// R6: P LDS round-trip eliminated via bf16x2 pack + v_permlane16_swap_b32;
//     V^T stored kt-permuted: pos = (quad&1)<<5 | (((quad>>1)<<1|(mt&1))<<3)
//     | ((mt>>1)<<2) (+r) within each 64-aligned t-block.
// R7: 64 q/wave attn (4 q-sets share K/V frags); logit scale folded into Q.
// R8 (reverted): 256^2 8-phase GEMM was ~neutral at this shape (proj grid =
//     128 blocks = half the CUs idle; K=1024 -> NT=16 amortizes poorly).
//     GEMMs are back to the 128^2 m97 structure.
// R9: attn stall analysis: per-chunk pipe work is ~1K cyc but the measured
//     period is ~6.6K cyc/wave -> waves stall at barriers. Two causes fixed:
//     (a) __syncthreads drains vmcnt(0) twice per chunk, exposing the K/V
//         global prefetch latency. Replaced with raw s_barrier (+explicit
//         lgkmcnt(0) on the writer side only); the prefetch's vmcnt wait
//         happens counted, at the ds_write use. sched_barrier(0) pins.
//     (b) FETCH_SIZE=139MB (vs 48MB unique) showed K/V re-reads missing L2:
//         default grid spreads one bh's 8 x-blocks over 8 XCDs, so each XCD
//         touches all 64 bh (32MB >> 4MB L2). 1-D grid 512 with decode
//         bh=(l&7)*8+((l>>3)&7), xbq=l>>6 gives each XCD 8 bh (4MB = L2) and
//         same-CU blocks (l, l+256) the SAME bh (L1 reuse of K/V reads).

#define B_ 4
#define T_ 2048
#define C_ 1024
#define H_ 16
#define D_ 64

// 0.125 * log2(e): attention scale folded into Q at projection time (R7b).
#define QSCALE 0.18033688011112042f

typedef float  f32x4  __attribute__((ext_vector_type(4)));
typedef __bf16 bf16x8 __attribute__((ext_vector_type(8)));
typedef __bf16 bf16x4 __attribute__((ext_vector_type(4)));
typedef __bf16 bf16x2 __attribute__((ext_vector_type(2)));
typedef unsigned uint2v __attribute__((ext_vector_type(2)));

typedef const __attribute__((address_space(1))) void gv_t;
typedef __attribute__((address_space(3))) void lds_t;

__device__ __forceinline__ void async_load16(const void* g, void* l) {
  __builtin_amdgcn_global_load_lds((gv_t*)g, (lds_t*)l, 16, 0, 0);
}

__device__ __forceinline__ float fast_exp2(float x) {
#if __has_builtin(__builtin_amdgcn_exp2f)
  return __builtin_amdgcn_exp2f(x);
#else
  return exp2f(x);
#endif
}

// v_permlane16_swap_b32: newA rows = [A0,B0,A2,B2], newB rows = [A1,B1,A3,B3]
__device__ __forceinline__ void pl16_swap(unsigned& a, unsigned& b) {
#if __has_builtin(__builtin_amdgcn_permlane16_swap)
  uint2v r = __builtin_amdgcn_permlane16_swap(a, b, false, false);
  a = r[0];
  b = r[1];
#else
  asm("v_permlane16_swap_b32 %0, %1" : "+v"(a), "+v"(b));
#endif
}

// ---------------------------------------------------------------- cast x
__global__ __launch_bounds__(256) void cast_f32_bf16(
    const float* __restrict__ in, __bf16* __restrict__ out, int n) {
  int i = (blockIdx.x * 256 + threadIdx.x) * 8;
  if (i >= n) return;
  float4 a = *(const float4*)(in + i);
  float4 b = *(const float4*)(in + i + 4);
  bf16x8 o;
  o[0] = (__bf16)a.x; o[1] = (__bf16)a.y; o[2] = (__bf16)a.z; o[3] = (__bf16)a.w;
  o[4] = (__bf16)b.x; o[5] = (__bf16)b.y; o[6] = (__bf16)b.z; o[7] = (__bf16)b.w;
  *(bf16x8*)(out + i) = o;
}

// ------------------------------------------- W [K,N] fp32 -> W^T [N,K] bf16
__global__ __launch_bounds__(256) void transpose_cast_w(
    const float* __restrict__ W0, const float* __restrict__ W1,
    const float* __restrict__ W2, const float* __restrict__ W3,
    __bf16* __restrict__ out) {
  int z = blockIdx.z;
  const float* W = (z == 0) ? W0 : (z == 1) ? W1 : (z == 2) ? W2 : W3;
  __bf16* o = out + (size_t)z * (C_ * C_);
  __shared__ __align__(16) __bf16 sT[64][72];
  int tid = threadIdx.x;
  int n0 = blockIdx.x * 64, k0 = blockIdx.y * 64;
#pragma unroll
  for (int i = 0; i < 4; i++) {
    int s = tid + i * 256;
    int kr = s >> 4, nc = (s & 15) * 4;
    float4 v = *(const float4*)&W[(size_t)(k0 + kr) * C_ + n0 + nc];
    bf16x4 t;
    t[0] = (__bf16)v.x; t[1] = (__bf16)v.y; t[2] = (__bf16)v.z; t[3] = (__bf16)v.w;
    *(bf16x4*)&sT[kr][nc] = t;
  }
  __syncthreads();
#pragma unroll
  for (int i = 0; i < 2; i++) {
    int s = tid + i * 256;
    int nr = s >> 3, kc = (s & 7) * 8;
    bf16x8 ov;
#pragma unroll
    for (int j = 0; j < 8; j++) ov[j] = sT[kc + j][nr];
    *(bf16x8*)&o[(size_t)(n0 + nr) * C_ + k0 + kc] = ov;
  }
}

// ------------------------------------------------ m97-style GEMM, B^T input
// C[M,N] = (A[M,K](bf16) @ Bt[N,K](bf16)^T + bias) * scale
// EPI 0: row-major OutT.  EPI 1: V-transpose into Vt[b,h,d,t] with the R6
// kt-permutation applied within each 64-aligned t-block (packed b64 stores).
template <typename OutT, int EPI>
__device__ __forceinline__ void gemm_body(
    const __bf16* __restrict__ A, const __bf16* __restrict__ Bt,
    const float* __restrict__ bias, OutT* __restrict__ C, int M, int N, int K,
    float scale) {
  __shared__ __align__(16) __bf16 sA[128 * 32];  // no pad: global_load_lds needs contig
  __shared__ __align__(16) __bf16 sB[128 * 32];
  int tid = threadIdx.x, lane = tid & 63, wave = tid >> 6;
  int lr = lane & 15, quad = lane >> 4;
  int m0 = blockIdx.y * 128, n0 = blockIdx.x * 128;
  int wm = (wave & 1) * 64, wn = (wave >> 1) * 64;

  const f32x4 zero = {0.f, 0.f, 0.f, 0.f};
  f32x4 acc[4][4];
#pragma unroll
  for (int i = 0; i < 4; i++)
#pragma unroll
    for (int j = 0; j < 4; j++) acc[i][j] = zero;

  for (int k0 = 0; k0 < K; k0 += 32) {
    __syncthreads();
#pragma unroll
    for (int i = 0; i < 2; i++) {
      int s = tid + i * 256;
      int r = s >> 2, c8 = (s & 3) * 8;
      async_load16(A + (size_t)(m0 + r) * K + k0 + c8, &sA[s * 8]);
      async_load16(Bt + (size_t)(n0 + r) * K + k0 + c8, &sB[s * 8]);
    }
    __syncthreads();
    bf16x8 af[4], bfr[4];
#pragma unroll
    for (int mt = 0; mt < 4; mt++)
      af[mt] = *(const bf16x8*)&sA[(wm + mt * 16 + lr) * 32 + quad * 8];
#pragma unroll
    for (int nt = 0; nt < 4; nt++)
      bfr[nt] = *(const bf16x8*)&sB[(wn + nt * 16 + lr) * 32 + quad * 8];
#pragma unroll
    for (int mt = 0; mt < 4; mt++)
#pragma unroll
      for (int nt = 0; nt < 4; nt++)
        acc[mt][nt] = __builtin_amdgcn_mfma_f32_16x16x32_bf16(
            af[mt], bfr[nt], acc[mt][nt], 0, 0, 0);
  }
  // C/D layout: col=lane&15 (n), row=mt*16+quad*4+reg (m)  [m89/m91]
  if (EPI == 0) {
#pragma unroll
    for (int mt = 0; mt < 4; mt++) {
#pragma unroll
      for (int nt = 0; nt < 4; nt++) {
        int n = n0 + wn + nt * 16 + lr;
        float bv = bias[n];
#pragma unroll
        for (int r = 0; r < 4; r++) {
          int m = m0 + wm + mt * 16 + quad * 4 + r;
          C[(size_t)m * N + n] = (OutT)((acc[mt][nt][r] + bv) * scale);
        }
      }
    }
  } else {
    // V^T: Vt[(b*16+h)*64+d][t_permuted] = V[t][n=h*64+d] + bias
    int bb = m0 >> 11;               // m0 / T_ (tiles never straddle batches)
    int mloc0 = (m0 & (T_ - 1)) + wm;  // 64-aligned
    __bf16* Ct = (__bf16*)C;
#pragma unroll
    for (int mt = 0; mt < 4; mt++) {
      int pos = ((quad & 1) << 5) | ((((quad >> 1) << 1) | (mt & 1)) << 3) |
                ((mt >> 1) << 2);
#pragma unroll
      for (int nt = 0; nt < 4; nt++) {
        int n = n0 + wn + nt * 16 + lr;
        float bv = bias[n];
        bf16x4 ov;
#pragma unroll
        for (int r = 0; r < 4; r++) ov[r] = (__bf16)(acc[mt][nt][r] + bv);
        *(bf16x4*)&Ct[((size_t)bb * C_ + n) * T_ + mloc0 + pos] = ov;
      }
    }
  }
}

__global__ __launch_bounds__(256) void gemm_qkv_kernel(
    const __bf16* __restrict__ A, const __bf16* __restrict__ WT,
    const float* __restrict__ b0, const float* __restrict__ b1,
    const float* __restrict__ b2, __bf16* __restrict__ qkbase,
    __bf16* __restrict__ Vt) {
  int z = blockIdx.z;
  if (z == 2) {
    gemm_body<__bf16, 1>(A, WT + (size_t)2 * C_ * C_, b2, Vt, B_ * T_, C_, C_,
                         1.0f);
  } else {
    const float* bias = (z == 0) ? b0 : b1;
    float scale = (z == 0) ? QSCALE : 1.0f;  // R7b: fold attn scale into Q
    gemm_body<__bf16, 0>(A, WT + (size_t)z * C_ * C_, bias,
                         qkbase + (size_t)z * (B_ * T_) * C_, B_ * T_, C_, C_,
                         scale);
  }
}

__global__ __launch_bounds__(256) void gemm_proj_kernel(
    const __bf16* __restrict__ A, const __bf16* __restrict__ Bt,
    const float* __restrict__ bias, float* __restrict__ C) {
  gemm_body<float, 0>(A, Bt, bias, C, B_ * T_, C_, C_, 1.0f);
}

// ----------------- attention, operand-swapped, no-max softmax, 64 q / wave
// grid 512 (1-D, XCD-clustered), 256 thr. Each wave: 64 q rows (4 frag sets),
// K chunk 64. Raw s_barrier protocol (R9a): barrier A (reads of chunk c-1 are
// complete via each wave's MFMA lgkm waits) -> staging ds_writes (vmcnt waits
// happen counted, at the kreg/vreg use) -> lgkmcnt(0) + barrier B -> prefetch
// chunk c+1 (never drained) -> compute.
__global__ __launch_bounds__(256) void attn_kernel(
    const __bf16* __restrict__ Q, const __bf16* __restrict__ K,
    const __bf16* __restrict__ Vt, __bf16* __restrict__ O) {
  __shared__ __align__(16) __bf16 sK[64 * 72];      // [kt][d]
  __shared__ __align__(16) __bf16 sV[64 * 72];      // [d][kt_permuted]
  int tid = threadIdx.x, wave = tid >> 6, lane = tid & 63;
  int lr = lane & 15, quad = lane >> 4;
  // R9b: XCD-clustered decode. l%8 = XCD class -> 8 bh per XCD (K/V = 4MB,
  // L2-resident); same-CU blocks (l, l+256) share bh (L1 reuse).
  int l = blockIdx.x;
  int bh = (l & 7) * 8 + ((l >> 3) & 7);
  int xbq = l >> 6;  // 0..7
  int b = bh >> 4, h = bh & 15;
  int qw = xbq * 256 + wave * 64;

  bf16x8 aq[4][2];
#pragma unroll
  for (int s = 0; s < 4; s++) {
    const __bf16* qp =
        Q + ((size_t)(b * T_ + qw + s * 16 + lr)) * C_ + h * D_ + quad * 8;
    aq[s][0] = *(const bf16x8*)qp;
    aq[s][1] = *(const bf16x8*)(qp + 32);
  }

  bf16x8 onesf;
#pragma unroll
  for (int j = 0; j < 8; j++) onesf[j] = (__bf16)1.0f;

  const f32x4 zero = {0.f, 0.f, 0.f, 0.f};
  f32x4 accO[4][4];
  f32x4 accL[4] = {zero, zero, zero, zero};
#pragma unroll
  for (int s = 0; s < 4; s++)
#pragma unroll
    for (int d = 0; d < 4; d++) accO[s][d] = zero;

  int srow[2], sc8[2];
#pragma unroll
  for (int i = 0; i < 2; i++) {
    int s = tid + i * 256;
    srow[i] = s >> 3;
    sc8[i] = (s & 7) * 8;
  }

  bf16x8 kreg[2], vreg[2];
#pragma unroll
  for (int i = 0; i < 2; i++) {
    kreg[i] = *(const bf16x8*)(K + ((size_t)(b * T_ + srow[i])) * C_ + h * D_ + sc8[i]);
    vreg[i] = *(const bf16x8*)(Vt + ((size_t)(bh * D_ + srow[i])) * T_ + sc8[i]);
  }

  for (int k0 = 0; k0 < T_; k0 += 64) {
    // barrier A: protect previous chunk's readers from the writes below.
    // Each wave's LDS reads completed before its last MFMA (lgkm waits), so
    // no waitcnt is needed here — raw s_barrier suffices.
    __builtin_amdgcn_sched_barrier(0);
    __builtin_amdgcn_s_barrier();
    __builtin_amdgcn_sched_barrier(0);
#pragma unroll
    for (int i = 0; i < 2; i++) {
      *(bf16x8*)&sK[srow[i] * 72 + sc8[i]] = kreg[i];
      *(bf16x8*)&sV[srow[i] * 72 + sc8[i]] = vreg[i];
    }
    // barrier B: writes visible to all waves. lgkmcnt(0) ensures this wave's
    // ds_writes completed; no vmcnt drain (the old __syncthreads stalled on
    // the in-flight prefetch here — R9a removes that).
    __builtin_amdgcn_sched_barrier(0);
    asm volatile("s_waitcnt lgkmcnt(0)" ::: "memory");
    __builtin_amdgcn_s_barrier();
    __builtin_amdgcn_sched_barrier(0);

    if (k0 + 64 < T_) {
      int kn = k0 + 64;
#pragma unroll
      for (int i = 0; i < 2; i++) {
        kreg[i] = *(const bf16x8*)(K + ((size_t)(b * T_ + kn + srow[i])) * C_ + h * D_ + sc8[i]);
        vreg[i] = *(const bf16x8*)(Vt + ((size_t)(bh * D_ + srow[i])) * T_ + kn + sc8[i]);
      }
    }

    // K fragments: 8 LDS reads per chunk, shared by all 4 q-sets (R7a).
    bf16x8 bkf[4][2];
#pragma unroll
    for (int nt = 0; nt < 4; nt++) {
      bkf[nt][0] = *(const bf16x8*)&sK[(nt * 16 + lr) * 72 + quad * 8];
      bkf[nt][1] = *(const bf16x8*)&sK[(nt * 16 + lr) * 72 + 32 + quad * 8];
    }

    bf16x8 bpA[4], bpB[4];
#pragma unroll
    for (int s = 0; s < 4; s++) {
      unsigned pw[4][2];
#pragma unroll
      for (int nt = 0; nt < 4; nt++) {
        f32x4 z = zero;
        z = __builtin_amdgcn_mfma_f32_16x16x32_bf16(bkf[nt][0], aq[s][0], z, 0, 0, 0);
        z = __builtin_amdgcn_mfma_f32_16x16x32_bf16(bkf[nt][1], aq[s][1], z, 0, 0, 0);
        union { bf16x2 h; unsigned u; } t0, t1;
        t0.h[0] = (__bf16)fast_exp2(z[0]);
        t0.h[1] = (__bf16)fast_exp2(z[1]);
        t1.h[0] = (__bf16)fast_exp2(z[2]);
        t1.h[1] = (__bf16)fast_exp2(z[3]);
        pw[nt][0] = t0.u;
        pw[nt][1] = t1.u;
      }
      unsigned a0 = pw[0][0], b0 = pw[1][0]; pl16_swap(a0, b0);
      unsigned a1 = pw[0][1], b1 = pw[1][1]; pl16_swap(a1, b1);
      unsigned a2 = pw[2][0], b2 = pw[3][0]; pl16_swap(a2, b2);
      unsigned a3 = pw[2][1], b3 = pw[3][1]; pl16_swap(a3, b3);
      union { unsigned u[4]; bf16x8 v; } pA, pB;
      pA.u[0] = a0; pA.u[1] = a1; pA.u[2] = a2; pA.u[3] = a3;
      pB.u[0] = b0; pB.u[1] = b1; pB.u[2] = b2; pB.u[3] = b3;
      bpA[s] = pA.v;
      bpB[s] = pB.v;
      accL[s] = __builtin_amdgcn_mfma_f32_16x16x32_bf16(onesf, bpA[s], accL[s], 0, 0, 0);
      accL[s] = __builtin_amdgcn_mfma_f32_16x16x32_bf16(onesf, bpB[s], accL[s], 0, 0, 0);
    }
#pragma unroll
    for (int dt = 0; dt < 4; dt++) {
      bf16x8 av0 = *(const bf16x8*)&sV[(dt * 16 + lr) * 72 + quad * 8];
      bf16x8 av1 = *(const bf16x8*)&sV[(dt * 16 + lr) * 72 + 32 + quad * 8];
#pragma unroll
      for (int s = 0; s < 4; s++) {
        accO[s][dt] = __builtin_amdgcn_mfma_f32_16x16x32_bf16(av0, bpA[s], accO[s][dt], 0, 0, 0);
        accO[s][dt] = __builtin_amdgcn_mfma_f32_16x16x32_bf16(av1, bpB[s], accO[s][dt], 0, 0, 0);
      }
    }
  }

#pragma unroll
  for (int s = 0; s < 4; s++) {
    float inv = 1.0f / accL[s][0];
    __bf16* op =
        O + ((size_t)(b * T_ + qw + s * 16 + lr)) * C_ + h * D_ + quad * 4;
#pragma unroll
    for (int dt = 0; dt < 4; dt++) {
      bf16x4 ov;
#pragma unroll
      for (int r = 0; r < 4; r++) ov[r] = (__bf16)(accO[s][dt][r] * inv);
      *(bf16x4*)&op[dt * 16] = ov;
    }
  }
}

// ------------------------------------------------------------------ launch
extern "C" void kernel_launch(void* const* d_in, const int* in_sizes, int n_in,
                              void* d_out, int out_size, void* d_ws, size_t ws_size,
                              hipStream_t stream) {
  const float* x  = (const float*)d_in[0];
  const float* Wq = (const float*)d_in[1];
  const float* bq = (const float*)d_in[2];
  const float* Wk = (const float*)d_in[3];
  const float* bk = (const float*)d_in[4];
  const float* Wv = (const float*)d_in[5];
  const float* bv = (const float*)d_in[6];
  const float* Wp = (const float*)d_in[7];
  const float* bp = (const float*)d_in[8];
  float* out = (float*)d_out;

  char* ws = (char*)d_ws;
  const size_t MB = 1024 * 1024;
  __bf16* xb    = (__bf16*)(ws + 0 * MB);   // 16 MB
  __bf16* WT    = (__bf16*)(ws + 16 * MB);  // 8 MB
  __bf16* Qb    = (__bf16*)(ws + 24 * MB);  // Q 16 MB (pre-scaled by QSCALE)
  __bf16* Kb    = Qb + (size_t)(B_ * T_) * C_;   // K 16 MB
  __bf16* Vt    = Kb + (size_t)(B_ * T_) * C_;   // V^T 16 MB (R6-permuted)
  __bf16* attnb = (__bf16*)(ws + 72 * MB);  // 16 MB; total 88 MB
  __bf16* WpT   = WT + (size_t)3 * C_ * C_;

  cast_f32_bf16<<<dim3(4096), dim3(256), 0, stream>>>(x, xb, B_ * T_ * C_);
  transpose_cast_w<<<dim3(16, 16, 4), dim3(256), 0, stream>>>(Wq, Wk, Wv, Wp, WT);
  gemm_qkv_kernel<<<dim3(8, 64, 3), dim3(256), 0, stream>>>(xb, WT, bq, bk, bv, Qb, Vt);
  attn_kernel<<<dim3(512), dim3(256), 0, stream>>>(Qb, Kb, Vt, attnb);
  gemm_proj_kernel<<<dim3(8, 64), dim3(256), 0, stream>>>(attnb, WpT, bp, out);
}

// Round 6
// 268.243 us; speedup vs baseline: 1.0625x; 1.0087x over previous
//
#include <hip/hip_runtime.h>

// MultiHeadAttention: B=4 T=2048 C=1024 H=16 D=64, fp32 in/out, bf16 MFMA internally.
//
// Pipeline (all on `stream`):
//   1. cast_f32_bf16:    x (fp32 [8192,1024]) -> xb bf16
//   2. transpose_cast_w: Wq,Wk,Wv,Wp (fp32 [K,N]) -> WT bf16 [N,K] (B^T form)
//   3. gemm_qkv:         Q/K = xb @ W^T + b (bf16 [b,t,h,d]); Q pre-scaled by
//                        0.125*log2(e) (R7); V written TRANSPOSED as Vt
//                        [b,h,d,t] (kt-permuted, R6); XCD-clustered grid (R10)
//   4. attn_kernel:      flash attention, operand-swapped, 64 q/wave (R7),
//                        XCD-clustered grid + raw barriers (R9)
//   5. gemm_proj:        out = attn @ Wp^T + bp, fp32; XCD-clustered (R10)
//
// R6: P LDS round-trip eliminated via bf16x2 pack + v_permlane16_swap_b32;
//     V^T stored kt-permuted: pos = (quad&1)<<5 | (((quad>>1)<<1|(mt&1))<<3)
//     | ((mt>>1)<<2) (+r) within each 64-aligned t-block.
// R7: 64 q/wave attn (4 q-sets share K/V frags); logit scale folded into Q.
// R9: attn raw-barrier protocol + XCD-clustered attn grid: FETCH 139->24.6MB
//     (proves the l%8=XCD round-robin model); dur unchanged -> attn is
//     issue-bound (MfmaUtil 37.5 + VALUBusy 46.5), not BW-bound.
// R10: the GEMMs were HBM-bound by A-panel re-fetch: grid (8,64,z) puts the
//     8 n-tiles of each A-row on 8 DIFFERENT XCDs (linear id = x + 8y), so
//     every XCD re-fetches all of A (~450MB qkv, ~170MB proj ~= 100us HBM).
//     1-D grid + decode {xcd=l&7; per xcd: 8 m-rows x 8 n-tiles per z} makes
//     the per-XCD working set A 2MB + B 2MB = 4MB = L2. Expected ~4x traffic
//     cut; GEMMs become structure-bound (~65-75us qkv, ~25us proj).

#define B_ 4
#define T_ 2048
#define C_ 1024
#define H_ 16
#define D_ 64

// 0.125 * log2(e): attention scale folded into Q at projection time (R7b).
#define QSCALE 0.18033688011112042f

typedef float  f32x4  __attribute__((ext_vector_type(4)));
typedef __bf16 bf16x8 __attribute__((ext_vector_type(8)));
typedef __bf16 bf16x4 __attribute__((ext_vector_type(4)));
typedef __bf16 bf16x2 __attribute__((ext_vector_type(2)));
typedef unsigned uint2v __attribute__((ext_vector_type(2)));

typedef const __attribute__((address_space(1))) void gv_t;
typedef __attribute__((address_space(3))) void lds_t;

__device__ __forceinline__ void async_load16(const void* g, void* l) {
  __builtin_amdgcn_global_load_lds((gv_t*)g, (lds_t*)l, 16, 0, 0);
}

__device__ __forceinline__ float fast_exp2(float x) {
#if __has_builtin(__builtin_amdgcn_exp2f)
  return __builtin_amdgcn_exp2f(x);
#else
  return exp2f(x);
#endif
}

// v_permlane16_swap_b32: newA rows = [A0,B0,A2,B2], newB rows = [A1,B1,A3,B3]
__device__ __forceinline__ void pl16_swap(unsigned& a, unsigned& b) {
#if __has_builtin(__builtin_amdgcn_permlane16_swap)
  uint2v r = __builtin_amdgcn_permlane16_swap(a, b, false, false);
  a = r[0];
  b = r[1];
#else
  asm("v_permlane16_swap_b32 %0, %1" : "+v"(a), "+v"(b));
#endif
}

// ---------------------------------------------------------------- cast x
__global__ __launch_bounds__(256) void cast_f32_bf16(
    const float* __restrict__ in, __bf16* __restrict__ out, int n) {
  int i = (blockIdx.x * 256 + threadIdx.x) * 8;
  if (i >= n) return;
  float4 a = *(const float4*)(in + i);
  float4 b = *(const float4*)(in + i + 4);
  bf16x8 o;
  o[0] = (__bf16)a.x; o[1] = (__bf16)a.y; o[2] = (__bf16)a.z; o[3] = (__bf16)a.w;
  o[4] = (__bf16)b.x; o[5] = (__bf16)b.y; o[6] = (__bf16)b.z; o[7] = (__bf16)b.w;
  *(bf16x8*)(out + i) = o;
}

// ------------------------------------------- W [K,N] fp32 -> W^T [N,K] bf16
__global__ __launch_bounds__(256) void transpose_cast_w(
    const float* __restrict__ W0, const float* __restrict__ W1,
    const float* __restrict__ W2, const float* __restrict__ W3,
    __bf16* __restrict__ out) {
  int z = blockIdx.z;
  const float* W = (z == 0) ? W0 : (z == 1) ? W1 : (z == 2) ? W2 : W3;
  __bf16* o = out + (size_t)z * (C_ * C_);
  __shared__ __align__(16) __bf16 sT[64][72];
  int tid = threadIdx.x;
  int n0 = blockIdx.x * 64, k0 = blockIdx.y * 64;
#pragma unroll
  for (int i = 0; i < 4; i++) {
    int s = tid + i * 256;
    int kr = s >> 4, nc = (s & 15) * 4;
    float4 v = *(const float4*)&W[(size_t)(k0 + kr) * C_ + n0 + nc];
    bf16x4 t;
    t[0] = (__bf16)v.x; t[1] = (__bf16)v.y; t[2] = (__bf16)v.z; t[3] = (__bf16)v.w;
    *(bf16x4*)&sT[kr][nc] = t;
  }
  __syncthreads();
#pragma unroll
  for (int i = 0; i < 2; i++) {
    int s = tid + i * 256;
    int nr = s >> 3, kc = (s & 7) * 8;
    bf16x8 ov;
#pragma unroll
    for (int j = 0; j < 8; j++) ov[j] = sT[kc + j][nr];
    *(bf16x8*)&o[(size_t)(n0 + nr) * C_ + k0 + kc] = ov;
  }
}

// ------------------------------------------------ m97-style GEMM, B^T input
// C[M,N] = (A[M,K](bf16) @ Bt[N,K](bf16)^T + bias) * scale
// EPI 0: row-major OutT.  EPI 1: V-transpose into Vt[b,h,d,t] with the R6
// kt-permutation applied within each 64-aligned t-block (packed b64 stores).
// m0/n0 passed in (R10: XCD-clustered 1-D grid decode in the callers).
template <typename OutT, int EPI>
__device__ __forceinline__ void gemm_body(
    const __bf16* __restrict__ A, const __bf16* __restrict__ Bt,
    const float* __restrict__ bias, OutT* __restrict__ C, int N, int K,
    float scale, int m0, int n0) {
  __shared__ __align__(16) __bf16 sA[128 * 32];  // no pad: global_load_lds needs contig
  __shared__ __align__(16) __bf16 sB[128 * 32];
  int tid = threadIdx.x, lane = tid & 63, wave = tid >> 6;
  int lr = lane & 15, quad = lane >> 4;
  int wm = (wave & 1) * 64, wn = (wave >> 1) * 64;

  const f32x4 zero = {0.f, 0.f, 0.f, 0.f};
  f32x4 acc[4][4];
#pragma unroll
  for (int i = 0; i < 4; i++)
#pragma unroll
    for (int j = 0; j < 4; j++) acc[i][j] = zero;

  for (int k0 = 0; k0 < K; k0 += 32) {
    __syncthreads();
#pragma unroll
    for (int i = 0; i < 2; i++) {
      int s = tid + i * 256;
      int r = s >> 2, c8 = (s & 3) * 8;
      async_load16(A + (size_t)(m0 + r) * K + k0 + c8, &sA[s * 8]);
      async_load16(Bt + (size_t)(n0 + r) * K + k0 + c8, &sB[s * 8]);
    }
    __syncthreads();
    bf16x8 af[4], bfr[4];
#pragma unroll
    for (int mt = 0; mt < 4; mt++)
      af[mt] = *(const bf16x8*)&sA[(wm + mt * 16 + lr) * 32 + quad * 8];
#pragma unroll
    for (int nt = 0; nt < 4; nt++)
      bfr[nt] = *(const bf16x8*)&sB[(wn + nt * 16 + lr) * 32 + quad * 8];
#pragma unroll
    for (int mt = 0; mt < 4; mt++)
#pragma unroll
      for (int nt = 0; nt < 4; nt++)
        acc[mt][nt] = __builtin_amdgcn_mfma_f32_16x16x32_bf16(
            af[mt], bfr[nt], acc[mt][nt], 0, 0, 0);
  }
  // C/D layout: col=lane&15 (n), row=mt*16+quad*4+reg (m)  [m89/m91]
  if (EPI == 0) {
#pragma unroll
    for (int mt = 0; mt < 4; mt++) {
#pragma unroll
      for (int nt = 0; nt < 4; nt++) {
        int n = n0 + wn + nt * 16 + lr;
        float bv = bias[n];
#pragma unroll
        for (int r = 0; r < 4; r++) {
          int m = m0 + wm + mt * 16 + quad * 4 + r;
          C[(size_t)m * N + n] = (OutT)((acc[mt][nt][r] + bv) * scale);
        }
      }
    }
  } else {
    // V^T: Vt[(b*16+h)*64+d][t_permuted] = V[t][n=h*64+d] + bias
    int bb = m0 >> 11;               // m0 / T_ (tiles never straddle batches)
    int mloc0 = (m0 & (T_ - 1)) + wm;  // 64-aligned
    __bf16* Ct = (__bf16*)C;
#pragma unroll
    for (int mt = 0; mt < 4; mt++) {
      int pos = ((quad & 1) << 5) | ((((quad >> 1) << 1) | (mt & 1)) << 3) |
                ((mt >> 1) << 2);
#pragma unroll
      for (int nt = 0; nt < 4; nt++) {
        int n = n0 + wn + nt * 16 + lr;
        float bv = bias[n];
        bf16x4 ov;
#pragma unroll
        for (int r = 0; r < 4; r++) ov[r] = (__bf16)(acc[mt][nt][r] + bv);
        *(bf16x4*)&Ct[((size_t)bb * C_ + n) * T_ + mloc0 + pos] = ov;
      }
    }
  }
}

// R10: 1-D grid 1536. xcd = l&7 owns 8 m-rows x 8 n-tiles per matrix z:
// working set per XCD per z = A 8x256KB + B 2MB = 4MB = L2.
__global__ __launch_bounds__(256) void gemm_qkv_kernel(
    const __bf16* __restrict__ A, const __bf16* __restrict__ WT,
    const float* __restrict__ b0, const float* __restrict__ b1,
    const float* __restrict__ b2, __bf16* __restrict__ qkbase,
    __bf16* __restrict__ Vt) {
  int l = blockIdx.x;
  int xcd = l & 7;
  int idx = l >> 3;        // 0..191
  int z = idx >> 6;        // 0..2
  int rem = idx & 63;      // 0..63
  int m0 = (xcd * 8 + (rem >> 3)) * 128;
  int n0 = (rem & 7) * 128;
  if (z == 2) {
    gemm_body<__bf16, 1>(A, WT + (size_t)2 * C_ * C_, b2, Vt, C_, C_, 1.0f,
                         m0, n0);
  } else {
    const float* bias = (z == 0) ? b0 : b1;
    float scale = (z == 0) ? QSCALE : 1.0f;  // R7b: fold attn scale into Q
    gemm_body<__bf16, 0>(A, WT + (size_t)z * C_ * C_, bias,
                         qkbase + (size_t)z * (B_ * T_) * C_, C_, C_, scale,
                         m0, n0);
  }
}

__global__ __launch_bounds__(256) void gemm_proj_kernel(
    const __bf16* __restrict__ A, const __bf16* __restrict__ Bt,
    const float* __restrict__ bias, float* __restrict__ C) {
  int l = blockIdx.x;
  int xcd = l & 7;
  int idx = l >> 3;        // 0..63
  int m0 = (xcd * 8 + (idx >> 3)) * 128;
  int n0 = (idx & 7) * 128;
  gemm_body<float, 0>(A, Bt, bias, C, C_, C_, 1.0f, m0, n0);
}

// ----------------- attention, operand-swapped, no-max softmax, 64 q / wave
// grid 512 (1-D, XCD-clustered), 256 thr. Each wave: 64 q rows (4 frag sets),
// K chunk 64. Raw s_barrier protocol (R9a).
__global__ __launch_bounds__(256) void attn_kernel(
    const __bf16* __restrict__ Q, const __bf16* __restrict__ K,
    const __bf16* __restrict__ Vt, __bf16* __restrict__ O) {
  __shared__ __align__(16) __bf16 sK[64 * 72];      // [kt][d]
  __shared__ __align__(16) __bf16 sV[64 * 72];      // [d][kt_permuted]
  int tid = threadIdx.x, wave = tid >> 6, lane = tid & 63;
  int lr = lane & 15, quad = lane >> 4;
  // R9b: XCD-clustered decode. l%8 = XCD class -> 8 bh per XCD (K/V = 4MB,
  // L2-resident); same-CU blocks (l, l+256) share bh (L1 reuse).
  int l = blockIdx.x;
  int bh = (l & 7) * 8 + ((l >> 3) & 7);
  int xbq = l >> 6;  // 0..7
  int b = bh >> 4, h = bh & 15;
  int qw = xbq * 256 + wave * 64;

  bf16x8 aq[4][2];
#pragma unroll
  for (int s = 0; s < 4; s++) {
    const __bf16* qp =
        Q + ((size_t)(b * T_ + qw + s * 16 + lr)) * C_ + h * D_ + quad * 8;
    aq[s][0] = *(const bf16x8*)qp;
    aq[s][1] = *(const bf16x8*)(qp + 32);
  }

  bf16x8 onesf;
#pragma unroll
  for (int j = 0; j < 8; j++) onesf[j] = (__bf16)1.0f;

  const f32x4 zero = {0.f, 0.f, 0.f, 0.f};
  f32x4 accO[4][4];
  f32x4 accL[4] = {zero, zero, zero, zero};
#pragma unroll
  for (int s = 0; s < 4; s++)
#pragma unroll
    for (int d = 0; d < 4; d++) accO[s][d] = zero;

  int srow[2], sc8[2];
#pragma unroll
  for (int i = 0; i < 2; i++) {
    int s = tid + i * 256;
    srow[i] = s >> 3;
    sc8[i] = (s & 7) * 8;
  }

  bf16x8 kreg[2], vreg[2];
#pragma unroll
  for (int i = 0; i < 2; i++) {
    kreg[i] = *(const bf16x8*)(K + ((size_t)(b * T_ + srow[i])) * C_ + h * D_ + sc8[i]);
    vreg[i] = *(const bf16x8*)(Vt + ((size_t)(bh * D_ + srow[i])) * T_ + sc8[i]);
  }

  for (int k0 = 0; k0 < T_; k0 += 64) {
    // barrier A: protect previous chunk's readers from the writes below.
    __builtin_amdgcn_sched_barrier(0);
    __builtin_amdgcn_s_barrier();
    __builtin_amdgcn_sched_barrier(0);
#pragma unroll
    for (int i = 0; i < 2; i++) {
      *(bf16x8*)&sK[srow[i] * 72 + sc8[i]] = kreg[i];
      *(bf16x8*)&sV[srow[i] * 72 + sc8[i]] = vreg[i];
    }
    // barrier B: writes visible to all waves; no vmcnt drain (R9a).
    __builtin_amdgcn_sched_barrier(0);
    asm volatile("s_waitcnt lgkmcnt(0)" ::: "memory");
    __builtin_amdgcn_s_barrier();
    __builtin_amdgcn_sched_barrier(0);

    if (k0 + 64 < T_) {
      int kn = k0 + 64;
#pragma unroll
      for (int i = 0; i < 2; i++) {
        kreg[i] = *(const bf16x8*)(K + ((size_t)(b * T_ + kn + srow[i])) * C_ + h * D_ + sc8[i]);
        vreg[i] = *(const bf16x8*)(Vt + ((size_t)(bh * D_ + srow[i])) * T_ + kn + sc8[i]);
      }
    }

    // K fragments: 8 LDS reads per chunk, shared by all 4 q-sets (R7a).
    bf16x8 bkf[4][2];
#pragma unroll
    for (int nt = 0; nt < 4; nt++) {
      bkf[nt][0] = *(const bf16x8*)&sK[(nt * 16 + lr) * 72 + quad * 8];
      bkf[nt][1] = *(const bf16x8*)&sK[(nt * 16 + lr) * 72 + 32 + quad * 8];
    }

    bf16x8 bpA[4], bpB[4];
#pragma unroll
    for (int s = 0; s < 4; s++) {
      unsigned pw[4][2];
#pragma unroll
      for (int nt = 0; nt < 4; nt++) {
        f32x4 z = zero;
        z = __builtin_amdgcn_mfma_f32_16x16x32_bf16(bkf[nt][0], aq[s][0], z, 0, 0, 0);
        z = __builtin_amdgcn_mfma_f32_16x16x32_bf16(bkf[nt][1], aq[s][1], z, 0, 0, 0);
        union { bf16x2 h; unsigned u; } t0, t1;
        t0.h[0] = (__bf16)fast_exp2(z[0]);
        t0.h[1] = (__bf16)fast_exp2(z[1]);
        t1.h[0] = (__bf16)fast_exp2(z[2]);
        t1.h[1] = (__bf16)fast_exp2(z[3]);
        pw[nt][0] = t0.u;
        pw[nt][1] = t1.u;
      }
      unsigned a0 = pw[0][0], b0 = pw[1][0]; pl16_swap(a0, b0);
      unsigned a1 = pw[0][1], b1 = pw[1][1]; pl16_swap(a1, b1);
      unsigned a2 = pw[2][0], b2 = pw[3][0]; pl16_swap(a2, b2);
      unsigned a3 = pw[2][1], b3 = pw[3][1]; pl16_swap(a3, b3);
      union { unsigned u[4]; bf16x8 v; } pA, pB;
      pA.u[0] = a0; pA.u[1] = a1; pA.u[2] = a2; pA.u[3] = a3;
      pB.u[0] = b0; pB.u[1] = b1; pB.u[2] = b2; pB.u[3] = b3;
      bpA[s] = pA.v;
      bpB[s] = pB.v;
      accL[s] = __builtin_amdgcn_mfma_f32_16x16x32_bf16(onesf, bpA[s], accL[s], 0, 0, 0);
      accL[s] = __builtin_amdgcn_mfma_f32_16x16x32_bf16(onesf, bpB[s], accL[s], 0, 0, 0);
    }
#pragma unroll
    for (int dt = 0; dt < 4; dt++) {
      bf16x8 av0 = *(const bf16x8*)&sV[(dt * 16 + lr) * 72 + quad * 8];
      bf16x8 av1 = *(const bf16x8*)&sV[(dt * 16 + lr) * 72 + 32 + quad * 8];
#pragma unroll
      for (int s = 0; s < 4; s++) {
        accO[s][dt] = __builtin_amdgcn_mfma_f32_16x16x32_bf16(av0, bpA[s], accO[s][dt], 0, 0, 0);
        accO[s][dt] = __builtin_amdgcn_mfma_f32_16x16x32_bf16(av1, bpB[s], accO[s][dt], 0, 0, 0);
      }
    }
  }

#pragma unroll
  for (int s = 0; s < 4; s++) {
    float inv = 1.0f / accL[s][0];
    __bf16* op =
        O + ((size_t)(b * T_ + qw + s * 16 + lr)) * C_ + h * D_ + quad * 4;
#pragma unroll
    for (int dt = 0; dt < 4; dt++) {
      bf16x4 ov;
#pragma unroll
      for (int r = 0; r < 4; r++) ov[r] = (__bf16)(accO[s][dt][r] * inv);
      *(bf16x4*)&op[dt * 16] = ov;
    }
  }
}

// ------------------------------------------------------------------ launch
extern "C" void kernel_launch(void* const* d_in, const int* in_sizes, int n_in,
                              void* d_out, int out_size, void* d_ws, size_t ws_size,
                              hipStream_t stream) {
  const float* x  = (const float*)d_in[0];
  const float* Wq = (const float*)d_in[1];
  const float* bq = (const float*)d_in[2];
  const float* Wk = (const float*)d_in[3];
  const float* bk = (const float*)d_in[4];
  const float* Wv = (const float*)d_in[5];
  const float* bv = (const float*)d_in[6];
  const float* Wp = (const float*)d_in[7];
  const float* bp = (const float*)d_in[8];
  float* out = (float*)d_out;

  char* ws = (char*)d_ws;
  const size_t MB = 1024 * 1024;
  __bf16* xb    = (__bf16*)(ws + 0 * MB);   // 16 MB
  __bf16* WT    = (__bf16*)(ws + 16 * MB);  // 8 MB
  __bf16* Qb    = (__bf16*)(ws + 24 * MB);  // Q 16 MB (pre-scaled by QSCALE)
  __bf16* Kb    = Qb + (size_t)(B_ * T_) * C_;   // K 16 MB
  __bf16* Vt    = Kb + (size_t)(B_ * T_) * C_;   // V^T 16 MB (R6-permuted)
  __bf16* attnb = (__bf16*)(ws + 72 * MB);  // 16 MB; total 88 MB
  __bf16* WpT   = WT + (size_t)3 * C_ * C_;

  cast_f32_bf16<<<dim3(4096), dim3(256), 0, stream>>>(x, xb, B_ * T_ * C_);
  transpose_cast_w<<<dim3(16, 16, 4), dim3(256), 0, stream>>>(Wq, Wk, Wv, Wp, WT);
  gemm_qkv_kernel<<<dim3(1536), dim3(256), 0, stream>>>(xb, WT, bq, bk, bv, Qb, Vt);
  attn_kernel<<<dim3(512), dim3(256), 0, stream>>>(Qb, Kb, Vt, attnb);
  gemm_proj_kernel<<<dim3(512), dim3(256), 0, stream>>>(attnb, WpT, bp, out);
}